// Round 9
// baseline (1537.617 us; speedup 1.0000x reference)
//
#include <hip/hip_runtime.h>
#include <hip/hip_bf16.h>

// ---------------------------------------------------------------------------
// GCN: 3x (GEMM -> sym-normalized aggregation(+self-loop) -> +bias -> ReLU)
//      -> global max pool per graph -> MLP head.  All fp32.
// GEMM (round-6 structure, VGPR<=128): BM=128, BK=32, 256 thr, 8x8 micro-tile;
//   W via global_load_lds; A staged transposed (pad+4); OUTPUT SLICE-MAJOR
//   [C/32][N][32] to enable channel-split aggregation.
// Agg: per-32-channel pass; gather slice is ~12.8MB (L2-friendly);
//   16 lanes/edge (float2), 4 edges/wave, 4-deep unroll; writes row-major h.
// ---------------------------------------------------------------------------

typedef float f4u __attribute__((ext_vector_type(4), aligned(4)));

__global__ void deg_count_kernel(const int* __restrict__ ei, int* __restrict__ cnt, int E) {
    int e = blockIdx.x * 256 + threadIdx.x;
    if (e < E) atomicAdd(&cnt[ei[E + e]], 1);
}

__global__ void deg_fin_kernel(const int* __restrict__ cnt, float* __restrict__ disq, int N) {
    int i = blockIdx.x * 256 + threadIdx.x;
    if (i < N) disq[i] = rsqrtf((float)cnt[i] + 1.0f);
}

// ---- 2-level exclusive scan of cnt[N] -> rp[N] (chunk = 1024 = 256 thr x 4)
__global__ void scan_pass1(const int* __restrict__ cnt, int* __restrict__ bsum, int N) {
    __shared__ int s[256];
    int t = threadIdx.x;
    int base = blockIdx.x * 1024 + t * 4;
    int sum = 0;
    #pragma unroll
    for (int j = 0; j < 4; ++j) { int idx = base + j; if (idx < N) sum += cnt[idx]; }
    s[t] = sum; __syncthreads();
    for (int off = 128; off; off >>= 1) {
        if (t < off) s[t] += s[t + off];
        __syncthreads();
    }
    if (t == 0) bsum[blockIdx.x] = s[0];
}

__global__ void scan_pass2(const int* __restrict__ bsum, int* __restrict__ boff,
                           int nchunks, int* __restrict__ rp, int N, int E) {
    __shared__ int s[256];
    int t = threadIdx.x;
    int v = (t < nchunks) ? bsum[t] : 0;
    s[t] = v; __syncthreads();
    for (int off = 1; off < 256; off <<= 1) {
        int x = (t >= off) ? s[t - off] : 0;
        __syncthreads();
        s[t] += x;
        __syncthreads();
    }
    boff[t] = s[t] - v;           // exclusive
    if (t == 0) rp[N] = E;
}

__global__ void scan_pass3(const int* __restrict__ cnt, const int* __restrict__ boff,
                           int* __restrict__ rp, int N) {
    __shared__ int s[256];
    int t = threadIdx.x;
    int base = blockIdx.x * 1024 + t * 4;
    int v[4]; int sum = 0;
    #pragma unroll
    for (int j = 0; j < 4; ++j) { int idx = base + j; v[j] = (idx < N) ? cnt[idx] : 0; sum += v[j]; }
    s[t] = sum; __syncthreads();
    for (int off = 1; off < 256; off <<= 1) {
        int x = (t >= off) ? s[t - off] : 0;
        __syncthreads();
        s[t] += x;
        __syncthreads();
    }
    int ex = s[t] - sum + boff[blockIdx.x];
    #pragma unroll
    for (int j = 0; j < 4; ++j) { int idx = base + j; if (idx < N) { rp[idx] = ex; ex += v[j]; } }
}

__global__ void scatter_kernel(const int* __restrict__ ei, const float* __restrict__ disq,
                               const int* __restrict__ rp, int* __restrict__ fill,
                               int2* __restrict__ esw, int E) {
    int e = blockIdx.x * 256 + threadIdx.x;
    if (e >= E) return;
    int s = ei[e];
    int d = ei[E + e];
    int pos = rp[d] + atomicAdd(&fill[d], 1);
    int2 p; p.x = s; p.y = __float_as_int(disq[s] * disq[d]);
    esw[pos] = p;
}

// ---- fp32 GEMM: Cs = A[N,K] @ W[K,BN], output SLICE-MAJOR [BN/32][N][32].
template <int BN>
__global__ __launch_bounds__(256, 4) void gemm_kernel(
    const float* __restrict__ A, const float* __restrict__ Wg,
    float* __restrict__ Cs, int N, int K)
{
    constexpr int BM = 128, BK = 32;
    constexpr int NB = (BN == 128) ? 2 : 1;
    constexpr int CHUNKS = (BK * BN) / 256;
    __shared__ float As[BK][BM + 4];
    __shared__ float Ws[BK][BN];
    const int tid = threadIdx.x;
    const int tr = tid >> 4;
    const int tc = tid & 15;
    const int wv = tid >> 6;
    const int ln = tid & 63;
    const long base = (long)blockIdx.x * BM;

    float acc[8][4 * NB];
    #pragma unroll
    for (int i = 0; i < 8; ++i)
        #pragma unroll
        for (int j = 0; j < 4 * NB; ++j) acc[i][j] = 0.f;

    for (int k0 = 0; k0 < K; k0 += BK) {
        // ---- stage W via global_load_lds
        #pragma unroll
        for (int c = wv; c < CHUNKS; c += 4) {
            int row, coloff;
            if constexpr (BN == 128) { row = k0 + c * 2 + (ln >> 5); coloff = (ln & 31) * 4; }
            else                     { row = k0 + c * 4 + (ln >> 4); coloff = (ln & 15) * 4; }
            if (row > K - 1) row = K - 1;   // clamped rows meet zero A -> 0
            const float* gp = &Wg[(long)row * BN + coloff];
            char* lp = ((char*)&Ws[0][0]) + c * 1024;
            __builtin_amdgcn_global_load_lds(
                (const __attribute__((address_space(1))) void*)gp,
                (__attribute__((address_space(3))) void*)lp, 16, 0, 0);
        }
        // ---- stage A transposed: As[k][m] = A[base+m][k0+k]
        #pragma unroll
        for (int t = 0; t < 4; ++t) {
            int i = tid + t * 256;                // 0..1023
            int r = i >> 3;                       // 0..127
            int kq = (i & 7) * 4;                 // 0,4,...,28
            long row = base + r;
            float f0 = 0.f, f1 = 0.f, f2 = 0.f, f3 = 0.f;
            if (row < N) {
                const float* ap = &A[row * K + k0 + kq];
                int rem = K - (k0 + kq);
                if (rem >= 4) {
                    f4u v = *(const f4u*)ap;      // dwordx4 @4B alignment
                    f0 = v.x; f1 = v.y; f2 = v.z; f3 = v.w;
                } else {
                    if (rem > 0) f0 = ap[0];
                    if (rem > 1) f1 = ap[1];
                    if (rem > 2) f2 = ap[2];
                }
            }
            As[kq + 0][r] = f0;
            As[kq + 1][r] = f1;
            As[kq + 2][r] = f2;
            As[kq + 3][r] = f3;
        }
        __syncthreads();
        #pragma unroll
        for (int k = 0; k < BK; ++k) {
            float4 a0 = *(const float4*)&As[k][tr * 4];
            float4 a1 = *(const float4*)&As[k][64 + tr * 4];
            float am[8] = {a0.x, a0.y, a0.z, a0.w, a1.x, a1.y, a1.z, a1.w};
            float4 w0 = *(const float4*)&Ws[k][tc * 4];
            if constexpr (NB == 2) {
                float4 w1 = *(const float4*)&Ws[k][64 + tc * 4];
                float wn[8] = {w0.x, w0.y, w0.z, w0.w, w1.x, w1.y, w1.z, w1.w};
                #pragma unroll
                for (int i = 0; i < 8; ++i)
                    #pragma unroll
                    for (int j = 0; j < 8; ++j) acc[i][j] += am[i] * wn[j];
            } else {
                float wn[4] = {w0.x, w0.y, w0.z, w0.w};
                #pragma unroll
                for (int i = 0; i < 8; ++i)
                    #pragma unroll
                    for (int j = 0; j < 4; ++j) acc[i][j] += am[i] * wn[j];
            }
        }
        __syncthreads();
    }
    // ---- epilogue: slice-major writes [col>>5][row][col&31]
    #pragma unroll
    for (int rb = 0; rb < 2; ++rb) {
        #pragma unroll
        for (int i = 0; i < 4; ++i) {
            long row = base + rb * 64 + tr * 4 + i;
            if (row < N) {
                int ai = rb * 4 + i;
                int c0 = tc * 4;
                float4 v0 = {acc[ai][0], acc[ai][1], acc[ai][2], acc[ai][3]};
                *(float4*)&Cs[(size_t)(c0 >> 5) * N * 32 + row * 32 + (c0 & 31)] = v0;
                if constexpr (NB == 2) {
                    int c1 = 64 + tc * 4;
                    float4 v1 = {acc[ai][4], acc[ai][5], acc[ai][6], acc[ai][7]};
                    *(float4*)&Cs[(size_t)(c1 >> 5) * N * 32 + row * 32 + (c1 & 31)] = v1;
                }
            }
        }
    }
}

// ---- channel-split aggregation, one 32-channel slice per launch.
// h[i][p*32+c] = relu( sum_e xwp[p][src_e][c]*nv_e + xwp[p][i][c]*disq^2 + b )
// One node per wave; 16 lanes/edge (float2), 4 edges per wave-load, 4-deep.
template <int C>
__global__ __launch_bounds__(256) void aggp_kernel(
    const float* __restrict__ xwp,    // slice-major [C/32][N][32]
    const float* __restrict__ disq,
    const int* __restrict__ rp, const int2* __restrict__ esw,
    const float* __restrict__ bias, float* __restrict__ h, int N, int p)
{
    int i = blockIdx.x * 4 + (threadIdx.x >> 6);
    if (i >= N) return;
    int lane = threadIdx.x & 63;
    int sub = lane >> 4;              // edge slot 0..3
    int col = lane & 15;              // float2 column within 32-ch row
    int e0 = rp[i], e1 = rp[i + 1];
    const float2* xw2 = (const float2*)(xwp + (size_t)p * N * 32);

    float2 a0{0.f,0.f}, a1{0.f,0.f}, a2{0.f,0.f}, a3{0.f,0.f};
    int e = e0 + sub;
    for (; e + 12 < e1; e += 16) {
        int2 p0 = esw[e];
        int2 p1 = esw[e + 4];
        int2 p2 = esw[e + 8];
        int2 p3 = esw[e + 12];
        float2 v0 = xw2[(long)p0.x * 16 + col];
        float2 v1 = xw2[(long)p1.x * 16 + col];
        float2 v2 = xw2[(long)p2.x * 16 + col];
        float2 v3 = xw2[(long)p3.x * 16 + col];
        float w0 = __int_as_float(p0.y), w1 = __int_as_float(p1.y);
        float w2 = __int_as_float(p2.y), w3 = __int_as_float(p3.y);
        a0.x += v0.x * w0; a0.y += v0.y * w0;
        a1.x += v1.x * w1; a1.y += v1.y * w1;
        a2.x += v2.x * w2; a2.y += v2.y * w2;
        a3.x += v3.x * w3; a3.y += v3.y * w3;
    }
    for (; e < e1; e += 4) {
        int2 p0 = esw[e];
        float2 v0 = xw2[(long)p0.x * 16 + col];
        float w0 = __int_as_float(p0.y);
        a0.x += v0.x * w0; a0.y += v0.y * w0;
    }
    a0.x += a1.x + a2.x + a3.x;
    a0.y += a1.y + a2.y + a3.y;
    a0.x += __shfl_xor(a0.x, 16, 64);
    a0.y += __shfl_xor(a0.y, 16, 64);
    a0.x += __shfl_xor(a0.x, 32, 64);
    a0.y += __shfl_xor(a0.y, 32, 64);
    if (sub == 0) {
        float ds = disq[i];
        float ws = ds * ds;
        float2 v = xw2[(long)i * 16 + col];
        float2 b = ((const float2*)(bias + p * 32))[col];
        float2 o;
        o.x = fmaxf(a0.x + v.x * ws + b.x, 0.f);
        o.y = fmaxf(a0.y + v.y * ws + b.y, 0.f);
        ((float2*)h)[(long)i * (C / 2) + p * 16 + col] = o;
    }
}

// ---- global max pool: batch sorted -> per-block running max, flush on change
__global__ __launch_bounds__(256) void pool_kernel(
    const float* __restrict__ h, const int* __restrict__ batch,
    float* __restrict__ g, int N)
{
    int c = threadIdx.x & 63;
    int slot = threadIdx.x >> 6;
    int base = blockIdx.x * 512;
    int end = base + 512; if (end > N) end = N;
    int cur = -1; float m = 0.f;
    for (int n = base + slot; n < end; n += 4) {
        int b = batch[n];
        float v = h[(long)n * 64 + c];
        if (b != cur) {
            if (cur >= 0) atomicMax((int*)&g[cur * 64 + c], __float_as_int(m));
            cur = b; m = v;
        } else {
            m = fmaxf(m, v);
        }
    }
    if (cur >= 0) atomicMax((int*)&g[cur * 64 + c], __float_as_int(m));
}

// ---- head: out[r] = relu(g[r]@Wh1+bh1) @ Wh2 + bh2
__global__ void head_kernel(const float* __restrict__ g, const float* __restrict__ Wh1,
                            const float* __restrict__ bh1, const float* __restrict__ Wh2,
                            const float* __restrict__ bh2, float* __restrict__ out, int G) {
    int r = threadIdx.x;
    if (r >= G) return;
    float hid[32];
    #pragma unroll
    for (int j = 0; j < 32; ++j) {
        float s = bh1[j];
        for (int k = 0; k < 64; ++k) s += g[r * 64 + k] * Wh1[k * 32 + j];
        hid[j] = fmaxf(s, 0.f);
    }
    float o = bh2[0];
    #pragma unroll
    for (int j = 0; j < 32; ++j) o += hid[j] * Wh2[j];
    out[r] = o;
}

extern "C" void kernel_launch(void* const* d_in, const int* in_sizes, int n_in,
                              void* d_out, int out_size, void* d_ws, size_t ws_size,
                              hipStream_t stream) {
    const float* x   = (const float*)d_in[0];
    const int*   ei  = (const int*)d_in[1];
    const int*   bat = (const int*)d_in[2];
    const float* W1  = (const float*)d_in[3];
    const float* b1  = (const float*)d_in[4];
    const float* W2  = (const float*)d_in[5];
    const float* b2  = (const float*)d_in[6];
    const float* W3  = (const float*)d_in[7];
    const float* b3  = (const float*)d_in[8];
    const float* Wh1 = (const float*)d_in[9];
    const float* bh1 = (const float*)d_in[10];
    const float* Wh2 = (const float*)d_in[11];
    const float* bh2 = (const float*)d_in[12];
    float* out = (float*)d_out;

    const int N = in_sizes[2];
    const int E = in_sizes[1] / 2;
    const int K1 = in_sizes[0] / N;   // 397
    const int G = out_size;           // 64

    char* wsp = (char*)d_ws;
    size_t off = 0;
    auto alloc = [&](size_t bytes) -> void* {
        void* p = wsp + off;
        off = (off + bytes + 255) & ~(size_t)255;
        return p;
    };
    int*   cnt  = (int*)alloc((size_t)N * 4);
    float* disq = (float*)alloc((size_t)N * 4);
    int*   rp   = (int*)alloc((size_t)(N + 1) * 4);
    int*   bsum = (int*)alloc(256 * 4);
    int*   boff = (int*)alloc(256 * 4);
    int2*  esw  = (int2*)alloc((size_t)E * 8);
    float* B0   = (float*)alloc((size_t)N * 128 * 4);   // slice-major GEMM out
    float* B1   = (float*)alloc((size_t)N * 128 * 4);   // row-major agg out
    float* g    = (float*)alloc((size_t)G * 64 * 4);

    const int nchunks = (N + 1023) / 1024;

    (void)hipMemsetAsync(cnt, 0, (size_t)N * 4, stream);
    deg_count_kernel<<<(E + 255) / 256, 256, 0, stream>>>(ei, cnt, E);
    deg_fin_kernel<<<(N + 255) / 256, 256, 0, stream>>>(cnt, disq, N);
    scan_pass1<<<nchunks, 256, 0, stream>>>(cnt, bsum, N);
    scan_pass2<<<1, 256, 0, stream>>>(bsum, boff, nchunks, rp, N, E);
    scan_pass3<<<nchunks, 256, 0, stream>>>(cnt, boff, rp, N);
    (void)hipMemsetAsync(cnt, 0, (size_t)N * 4, stream);
    scatter_kernel<<<(E + 255) / 256, 256, 0, stream>>>(ei, disq, rp, cnt, esw, E);

    int gblocks = (N + 127) / 128;
    int ablocks = (N + 3) / 4;
    // layer 1
    gemm_kernel<128><<<gblocks, 256, 0, stream>>>(x, W1, B0, N, K1);
    for (int p = 0; p < 4; ++p)
        aggp_kernel<128><<<ablocks, 256, 0, stream>>>(B0, disq, rp, esw, b1, B1, N, p);
    // layer 2
    gemm_kernel<128><<<gblocks, 256, 0, stream>>>(B1, W2, B0, N, 128);
    for (int p = 0; p < 4; ++p)
        aggp_kernel<128><<<ablocks, 256, 0, stream>>>(B0, disq, rp, esw, b2, B1, N, p);
    // layer 3
    gemm_kernel<64><<<gblocks, 256, 0, stream>>>(B1, W3, B0, N, 128);
    for (int p = 0; p < 2; ++p)
        aggp_kernel<64><<<ablocks, 256, 0, stream>>>(B0, disq, rp, esw, b3, B1, N, p);
    // pool + head
    (void)hipMemsetAsync(g, 0, (size_t)G * 64 * 4, stream);
    pool_kernel<<<(N + 511) / 512, 256, 0, stream>>>(B1, bat, g, N);
    head_kernel<<<1, 64, 0, stream>>>(g, Wh1, bh1, Wh2, bh2, out, G);
}

// Round 10
// 799.700 us; speedup vs baseline: 1.9227x; 1.9227x over previous
//
#include <hip/hip_runtime.h>
#include <hip/hip_bf16.h>

// ---------------------------------------------------------------------------
// GCN: 3x (GEMM -> sym-normalized aggregation(+self-loop) -> +bias -> ReLU)
//      -> global max pool per graph -> MLP head.  All fp32.
// GEMM: BM=128, BK=32, 256 thr, 8x8 micro-tile; W via global_load_lds;
//   A staged transposed (pad+4) with unaligned-float4 (dwordx4) loads.
// Agg: CSR gather, float4/lane, 4-deep unroll.
// Pool: running max per block, flush on graph change (batch sorted).
// ---------------------------------------------------------------------------

typedef float f4u __attribute__((ext_vector_type(4), aligned(4)));

__global__ void deg_count_kernel(const int* __restrict__ ei, int* __restrict__ cnt, int E) {
    int e = blockIdx.x * 256 + threadIdx.x;
    if (e < E) atomicAdd(&cnt[ei[E + e]], 1);
}

__global__ void deg_fin_kernel(const int* __restrict__ cnt, float* __restrict__ disq, int N) {
    int i = blockIdx.x * 256 + threadIdx.x;
    if (i < N) disq[i] = rsqrtf((float)cnt[i] + 1.0f);
}

// ---- 2-level exclusive scan of cnt[N] -> rp[N] (chunk = 1024 = 256 thr x 4)
__global__ void scan_pass1(const int* __restrict__ cnt, int* __restrict__ bsum, int N) {
    __shared__ int s[256];
    int t = threadIdx.x;
    int base = blockIdx.x * 1024 + t * 4;
    int sum = 0;
    #pragma unroll
    for (int j = 0; j < 4; ++j) { int idx = base + j; if (idx < N) sum += cnt[idx]; }
    s[t] = sum; __syncthreads();
    for (int off = 128; off; off >>= 1) {
        if (t < off) s[t] += s[t + off];
        __syncthreads();
    }
    if (t == 0) bsum[blockIdx.x] = s[0];
}

__global__ void scan_pass2(const int* __restrict__ bsum, int* __restrict__ boff,
                           int nchunks, int* __restrict__ rp, int N, int E) {
    __shared__ int s[256];
    int t = threadIdx.x;
    int v = (t < nchunks) ? bsum[t] : 0;
    s[t] = v; __syncthreads();
    for (int off = 1; off < 256; off <<= 1) {
        int x = (t >= off) ? s[t - off] : 0;
        __syncthreads();
        s[t] += x;
        __syncthreads();
    }
    boff[t] = s[t] - v;           // exclusive
    if (t == 0) rp[N] = E;
}

__global__ void scan_pass3(const int* __restrict__ cnt, const int* __restrict__ boff,
                           int* __restrict__ rp, int N) {
    __shared__ int s[256];
    int t = threadIdx.x;
    int base = blockIdx.x * 1024 + t * 4;
    int v[4]; int sum = 0;
    #pragma unroll
    for (int j = 0; j < 4; ++j) { int idx = base + j; v[j] = (idx < N) ? cnt[idx] : 0; sum += v[j]; }
    s[t] = sum; __syncthreads();
    for (int off = 1; off < 256; off <<= 1) {
        int x = (t >= off) ? s[t - off] : 0;
        __syncthreads();
        s[t] += x;
        __syncthreads();
    }
    int ex = s[t] - sum + boff[blockIdx.x];
    #pragma unroll
    for (int j = 0; j < 4; ++j) { int idx = base + j; if (idx < N) { rp[idx] = ex; ex += v[j]; } }
}

__global__ void scatter_kernel(const int* __restrict__ ei, const float* __restrict__ disq,
                               const int* __restrict__ rp, int* __restrict__ fill,
                               int2* __restrict__ esw, int E) {
    int e = blockIdx.x * 256 + threadIdx.x;
    if (e >= E) return;
    int s = ei[e];
    int d = ei[E + e];
    int pos = rp[d] + atomicAdd(&fill[d], 1);
    int2 p; p.x = s; p.y = __float_as_int(disq[s] * disq[d]);
    esw[pos] = p;
}

// ---- fp32 GEMM: C[N,BN] = A[N,K] @ W[K,BN]
// BM=128, BK=32, 256 threads (16x16). Thread (tr,tc) owns rows
// {tr*4..+3, 64+tr*4..+3}, cols {tc*4..+3, (64+tc*4..+3 if BN==128)}.
// A: transposed LDS (pad+4), reads 4-address broadcasts.
// W: staged by global_load_lds (linear LDS), reads 2-way aliasing (free).
template <int BN>
__global__ __launch_bounds__(256) void gemm_kernel(
    const float* __restrict__ A, const float* __restrict__ Wg,
    float* __restrict__ C, int N, int K)
{
    constexpr int BM = 128, BK = 32;
    constexpr int NB = (BN == 128) ? 2 : 1;
    constexpr int CHUNKS = (BK * BN) / 256;
    __shared__ float As[BK][BM + 4];
    __shared__ float Ws[BK][BN];
    const int tid = threadIdx.x;
    const int tr = tid >> 4;
    const int tc = tid & 15;
    const int wv = tid >> 6;
    const int ln = tid & 63;
    const long base = (long)blockIdx.x * BM;

    float acc[8][4 * NB];
    #pragma unroll
    for (int i = 0; i < 8; ++i)
        #pragma unroll
        for (int j = 0; j < 4 * NB; ++j) acc[i][j] = 0.f;

    for (int k0 = 0; k0 < K; k0 += BK) {
        // ---- stage W via global_load_lds
        #pragma unroll
        for (int c = wv; c < CHUNKS; c += 4) {
            int row, coloff;
            if constexpr (BN == 128) { row = k0 + c * 2 + (ln >> 5); coloff = (ln & 31) * 4; }
            else                     { row = k0 + c * 4 + (ln >> 4); coloff = (ln & 15) * 4; }
            if (row > K - 1) row = K - 1;   // clamped rows meet zero A -> 0
            const float* gp = &Wg[(long)row * BN + coloff];
            char* lp = ((char*)&Ws[0][0]) + c * 1024;
            __builtin_amdgcn_global_load_lds(
                (const __attribute__((address_space(1))) void*)gp,
                (__attribute__((address_space(3))) void*)lp, 16, 0, 0);
        }
        // ---- stage A transposed: As[k][m] = A[base+m][k0+k]
        #pragma unroll
        for (int t = 0; t < 4; ++t) {
            int i = tid + t * 256;                // 0..1023
            int r = i >> 3;                       // 0..127
            int kq = (i & 7) * 4;                 // 0,4,...,28
            long row = base + r;
            float f0 = 0.f, f1 = 0.f, f2 = 0.f, f3 = 0.f;
            if (row < N) {
                const float* ap = &A[row * K + k0 + kq];
                int rem = K - (k0 + kq);
                if (rem >= 4) {
                    f4u v = *(const f4u*)ap;      // dwordx4 @4B alignment
                    f0 = v.x; f1 = v.y; f2 = v.z; f3 = v.w;
                } else {
                    if (rem > 0) f0 = ap[0];
                    if (rem > 1) f1 = ap[1];
                    if (rem > 2) f2 = ap[2];
                }
            }
            As[kq + 0][r] = f0;
            As[kq + 1][r] = f1;
            As[kq + 2][r] = f2;
            As[kq + 3][r] = f3;
        }
        __syncthreads();
        #pragma unroll
        for (int k = 0; k < BK; ++k) {
            float4 a0 = *(const float4*)&As[k][tr * 4];
            float4 a1 = *(const float4*)&As[k][64 + tr * 4];
            float am[8] = {a0.x, a0.y, a0.z, a0.w, a1.x, a1.y, a1.z, a1.w};
            float4 w0 = *(const float4*)&Ws[k][tc * 4];
            if constexpr (NB == 2) {
                float4 w1 = *(const float4*)&Ws[k][64 + tc * 4];
                float wn[8] = {w0.x, w0.y, w0.z, w0.w, w1.x, w1.y, w1.z, w1.w};
                #pragma unroll
                for (int i = 0; i < 8; ++i)
                    #pragma unroll
                    for (int j = 0; j < 8; ++j) acc[i][j] += am[i] * wn[j];
            } else {
                float wn[4] = {w0.x, w0.y, w0.z, w0.w};
                #pragma unroll
                for (int i = 0; i < 8; ++i)
                    #pragma unroll
                    for (int j = 0; j < 4; ++j) acc[i][j] += am[i] * wn[j];
            }
        }
        __syncthreads();
    }
    #pragma unroll
    for (int rb = 0; rb < 2; ++rb) {
        #pragma unroll
        for (int i = 0; i < 4; ++i) {
            long row = base + rb * 64 + tr * 4 + i;
            if (row < N) {
                int ai = rb * 4 + i;
                float4 v0 = {acc[ai][0], acc[ai][1], acc[ai][2], acc[ai][3]};
                *(float4*)&C[row * BN + tc * 4] = v0;
                if constexpr (NB == 2) {
                    float4 v1 = {acc[ai][4], acc[ai][5], acc[ai][6], acc[ai][7]};
                    *(float4*)&C[row * BN + 64 + tc * 4] = v1;
                }
            }
        }
    }
}

// ---- aggregation: h[i] = relu( sum_e xw[src_e]*nv_e + xw[i]*disq[i]^2 + bias )
// 4 nodes/block (one wave each). float4 per lane; EPW edges per wave-load
// (2 for C=128, 4 for C=64); 4-deep unroll.
template <int C>
__global__ __launch_bounds__(256) void agg_kernel(
    const float* __restrict__ xw, const float* __restrict__ disq,
    const int* __restrict__ rp, const int2* __restrict__ esw,
    const float* __restrict__ bias, float* __restrict__ h, int N)
{
    int i = blockIdx.x * 4 + (threadIdx.x >> 6);
    if (i >= N) return;
    int lane = threadIdx.x & 63;
    int e0 = rp[i], e1 = rp[i + 1];
    const float4* xw4 = (const float4*)xw;
    constexpr int RQ = C / 4;
    constexpr int EPW = 64 / RQ;
    int sub = lane / RQ;
    int col = lane % RQ;

    float4 a0{0,0,0,0}, a1{0,0,0,0}, a2{0,0,0,0}, a3{0,0,0,0};
    int e = e0 + sub;
    for (; e + 3 * EPW < e1; e += 4 * EPW) {
        int2 p0 = esw[e];
        int2 p1 = esw[e + EPW];
        int2 p2 = esw[e + 2 * EPW];
        int2 p3 = esw[e + 3 * EPW];
        float4 v0 = xw4[(long)p0.x * RQ + col];
        float4 v1 = xw4[(long)p1.x * RQ + col];
        float4 v2 = xw4[(long)p2.x * RQ + col];
        float4 v3 = xw4[(long)p3.x * RQ + col];
        float w0 = __int_as_float(p0.y), w1 = __int_as_float(p1.y);
        float w2 = __int_as_float(p2.y), w3 = __int_as_float(p3.y);
        a0.x += v0.x * w0; a0.y += v0.y * w0; a0.z += v0.z * w0; a0.w += v0.w * w0;
        a1.x += v1.x * w1; a1.y += v1.y * w1; a1.z += v1.z * w1; a1.w += v1.w * w1;
        a2.x += v2.x * w2; a2.y += v2.y * w2; a2.z += v2.z * w2; a2.w += v2.w * w2;
        a3.x += v3.x * w3; a3.y += v3.y * w3; a3.z += v3.z * w3; a3.w += v3.w * w3;
    }
    for (; e < e1; e += EPW) {
        int2 p0 = esw[e];
        float4 v0 = xw4[(long)p0.x * RQ + col];
        float w0 = __int_as_float(p0.y);
        a0.x += v0.x * w0; a0.y += v0.y * w0; a0.z += v0.z * w0; a0.w += v0.w * w0;
    }
    a0.x += a1.x + a2.x + a3.x;
    a0.y += a1.y + a2.y + a3.y;
    a0.z += a1.z + a2.z + a3.z;
    a0.w += a1.w + a2.w + a3.w;
    #pragma unroll
    for (int m = RQ; m < 64; m <<= 1) {
        a0.x += __shfl_xor(a0.x, m, 64);
        a0.y += __shfl_xor(a0.y, m, 64);
        a0.z += __shfl_xor(a0.z, m, 64);
        a0.w += __shfl_xor(a0.w, m, 64);
    }
    if (sub == 0) {
        float ds = disq[i];
        float ws = ds * ds;
        float4 v = xw4[(long)i * RQ + col];
        float4 b = ((const float4*)bias)[col];
        float4 o;
        o.x = fmaxf(a0.x + v.x * ws + b.x, 0.f);
        o.y = fmaxf(a0.y + v.y * ws + b.y, 0.f);
        o.z = fmaxf(a0.z + v.z * ws + b.z, 0.f);
        o.w = fmaxf(a0.w + v.w * ws + b.w, 0.f);
        ((float4*)h)[(long)i * RQ + col] = o;
    }
}

// ---- global max pool: batch sorted -> per-block running max, flush on change
__global__ __launch_bounds__(256) void pool_kernel(
    const float* __restrict__ h, const int* __restrict__ batch,
    float* __restrict__ g, int N)
{
    int c = threadIdx.x & 63;
    int slot = threadIdx.x >> 6;
    int base = blockIdx.x * 512;
    int end = base + 512; if (end > N) end = N;
    int cur = -1; float m = 0.f;
    for (int n = base + slot; n < end; n += 4) {
        int b = batch[n];
        float v = h[(long)n * 64 + c];
        if (b != cur) {
            if (cur >= 0) atomicMax((int*)&g[cur * 64 + c], __float_as_int(m));
            cur = b; m = v;
        } else {
            m = fmaxf(m, v);
        }
    }
    if (cur >= 0) atomicMax((int*)&g[cur * 64 + c], __float_as_int(m));
}

// ---- head: out[r] = relu(g[r]@Wh1+bh1) @ Wh2 + bh2
__global__ void head_kernel(const float* __restrict__ g, const float* __restrict__ Wh1,
                            const float* __restrict__ bh1, const float* __restrict__ Wh2,
                            const float* __restrict__ bh2, float* __restrict__ out, int G) {
    int r = threadIdx.x;
    if (r >= G) return;
    float hid[32];
    #pragma unroll
    for (int j = 0; j < 32; ++j) {
        float s = bh1[j];
        for (int k = 0; k < 64; ++k) s += g[r * 64 + k] * Wh1[k * 32 + j];
        hid[j] = fmaxf(s, 0.f);
    }
    float o = bh2[0];
    #pragma unroll
    for (int j = 0; j < 32; ++j) o += hid[j] * Wh2[j];
    out[r] = o;
}

extern "C" void kernel_launch(void* const* d_in, const int* in_sizes, int n_in,
                              void* d_out, int out_size, void* d_ws, size_t ws_size,
                              hipStream_t stream) {
    const float* x   = (const float*)d_in[0];
    const int*   ei  = (const int*)d_in[1];
    const int*   bat = (const int*)d_in[2];
    const float* W1  = (const float*)d_in[3];
    const float* b1  = (const float*)d_in[4];
    const float* W2  = (const float*)d_in[5];
    const float* b2  = (const float*)d_in[6];
    const float* W3  = (const float*)d_in[7];
    const float* b3  = (const float*)d_in[8];
    const float* Wh1 = (const float*)d_in[9];
    const float* bh1 = (const float*)d_in[10];
    const float* Wh2 = (const float*)d_in[11];
    const float* bh2 = (const float*)d_in[12];
    float* out = (float*)d_out;

    const int N = in_sizes[2];
    const int E = in_sizes[1] / 2;
    const int K1 = in_sizes[0] / N;   // 397
    const int G = out_size;           // 64

    char* wsp = (char*)d_ws;
    size_t off = 0;
    auto alloc = [&](size_t bytes) -> void* {
        void* p = wsp + off;
        off = (off + bytes + 255) & ~(size_t)255;
        return p;
    };
    int*   cnt  = (int*)alloc((size_t)N * 4);
    float* disq = (float*)alloc((size_t)N * 4);
    int*   rp   = (int*)alloc((size_t)(N + 1) * 4);
    int*   bsum = (int*)alloc(256 * 4);
    int*   boff = (int*)alloc(256 * 4);
    int2*  esw  = (int2*)alloc((size_t)E * 8);
    float* B0   = (float*)alloc((size_t)N * 128 * 4);
    float* B1   = (float*)alloc((size_t)N * 128 * 4);
    float* g    = (float*)alloc((size_t)G * 64 * 4);

    const int nchunks = (N + 1023) / 1024;

    (void)hipMemsetAsync(cnt, 0, (size_t)N * 4, stream);
    deg_count_kernel<<<(E + 255) / 256, 256, 0, stream>>>(ei, cnt, E);
    deg_fin_kernel<<<(N + 255) / 256, 256, 0, stream>>>(cnt, disq, N);
    scan_pass1<<<nchunks, 256, 0, stream>>>(cnt, bsum, N);
    scan_pass2<<<1, 256, 0, stream>>>(bsum, boff, nchunks, rp, N, E);
    scan_pass3<<<nchunks, 256, 0, stream>>>(cnt, boff, rp, N);
    (void)hipMemsetAsync(cnt, 0, (size_t)N * 4, stream);
    scatter_kernel<<<(E + 255) / 256, 256, 0, stream>>>(ei, disq, rp, cnt, esw, E);

    int gblocks = (N + 127) / 128;
    int ablocks = (N + 3) / 4;
    // layer 1
    gemm_kernel<128><<<gblocks, 256, 0, stream>>>(x, W1, B0, N, K1);
    agg_kernel<128><<<ablocks, 256, 0, stream>>>(B0, disq, rp, esw, b1, B1, N);
    // layer 2
    gemm_kernel<128><<<gblocks, 256, 0, stream>>>(B1, W2, B0, N, 128);
    agg_kernel<128><<<ablocks, 256, 0, stream>>>(B0, disq, rp, esw, b2, B1, N);
    // layer 3
    gemm_kernel<64><<<gblocks, 256, 0, stream>>>(B1, W3, B0, N, 128);
    agg_kernel<64><<<ablocks, 256, 0, stream>>>(B0, disq, rp, esw, b3, B1, N);
    // pool + head
    (void)hipMemsetAsync(g, 0, (size_t)G * 64 * 4, stream);
    pool_kernel<<<(N + 511) / 512, 256, 0, stream>>>(B1, bat, g, N);
    head_kernel<<<1, 64, 0, stream>>>(g, Wh1, bh1, Wh2, bh2, out, G);
}